// Round 16
// baseline (247.202 us; speedup 1.0000x reference)
//
#include <hip/hip_runtime.h>
#include <stdint.h>

typedef unsigned short u16;
typedef __bf16 bf16x8 __attribute__((ext_vector_type(8)));
typedef float f32x4 __attribute__((ext_vector_type(4)));
typedef unsigned int u32x4 __attribute__((ext_vector_type(4)));
typedef unsigned int u32x2 __attribute__((ext_vector_type(2)));

typedef __attribute__((address_space(3))) void LDSV;
typedef __attribute__((address_space(1))) void GLV;

#define S_LEN 2048

__device__ __forceinline__ float bf2f(u16 u) {
  union { unsigned int i; float f; } v; v.i = ((unsigned int)u) << 16; return v.f;
}
__device__ __forceinline__ u16 f2bf(float f) {
  union { float f; unsigned int i; } v; v.f = f;
  unsigned int x = v.i;
  return (u16)((x + 0x7fffu + ((x >> 16) & 1u)) >> 16);
}
__device__ __forceinline__ unsigned int cvtpk(float lo, float hi) {
  unsigned int r;
  asm("v_cvt_pk_bf16_f32 %0, %1, %2" : "=v"(r) : "v"(lo), "v"(hi));
  return r;
}
__device__ __forceinline__ unsigned long long pack4(float4 v) {
  return (unsigned long long)f2bf(v.x)
       | ((unsigned long long)f2bf(v.y) << 16)
       | ((unsigned long long)f2bf(v.z) << 32)
       | ((unsigned long long)f2bf(v.w) << 48);
}

// ---------------- all casts in one dispatch ----------------
__global__ __launch_bounds__(256) void cast_all(
    const float* __restrict__ s0, u16* __restrict__ d0, long e0,
    const float* __restrict__ s1, u16* __restrict__ d1, long e1,
    const float* __restrict__ s2, u16* __restrict__ d2, long e2,
    const float* __restrict__ s3, u16* __restrict__ d3, long e3,
    const float* __restrict__ s4, u16* __restrict__ d4, long e4,
    const float* __restrict__ s5, u16* __restrict__ d5, long e5) {
  long i = (long)blockIdx.x * 256 + threadIdx.x;
  const float* src; u16* dst; long base; bool pad = false;
  if (i < e0)      { src = s0; dst = d0; base = 0; }
  else if (i < e1) { src = s1; dst = d1; base = e0; }
  else if (i < e2) { src = s2; dst = d2; base = e1; }
  else if (i < e3) { src = s3; dst = d3; base = e2; }
  else if (i < e4) { src = s4; dst = d4; base = e3; }
  else if (i < e5) { src = s5; dst = d5; base = e4; pad = true; }
  else return;
  long li = i - base;
  long elem0 = li * 4;
  unsigned long long r = 0;
  if (!pad || (elem0 >> 11) < 576)
    r = pack4(*(const float4*)(src + elem0));
  ((unsigned long long*)dst)[li] = r;
}

// ---------------- dual 256x256 8-phase NT GEMM (GEMM2 + GEMM4 in one grid) --------
#define MM_PHASE(QM, QN, BB)                                                     \
  __builtin_amdgcn_s_setprio(1);                                                 \
  {                                                                              \
    _Pragma("unroll") for (int mf = 0; mf < 4; ++mf) {                           \
      _Pragma("unroll") for (int nf = 0; nf < 2; ++nf) {                         \
        _Pragma("unroll") for (int kk = 0; kk < 2; ++kk) {                       \
          acc[(QM) * 4 + mf][(QN) * 2 + nf] =                                    \
              __builtin_amdgcn_mfma_f32_16x16x32_bf16(                           \
                  a[mf][kk], BB[nf][kk], acc[(QM) * 4 + mf][(QN) * 2 + nf],      \
                  0, 0, 0);                                                      \
        }                                                                        \
      }                                                                          \
    }                                                                            \
  }                                                                              \
  __builtin_amdgcn_s_setprio(0);

__global__ __launch_bounds__(512, 2) void gemm256_dual(const u16* __restrict__ Aq,
                                                       const u16* __restrict__ Bq,
                                                       u16* __restrict__ Cq,
                                                       const u16* __restrict__ Akv,
                                                       const u16* __restrict__ Bkv,
                                                       u16* __restrict__ KbN,
                                                       u16* __restrict__ Vc) {
  __shared__ u16 SMEM[65536];  // 128 KB
  const int tid = threadIdx.x;
  const int lane = tid & 63, wid = tid >> 6;
  const int l15 = lane & 15, l4 = lane >> 4;
  const int wm16 = (wid >> 2) * 16, wn16 = (wid & 3) * 16;

  const int id = blockIdx.x;
  const bool m0 = (id < 192);
  const u16* A = m0 ? Aq : Akv;
  const u16* B = m0 ? Bq : Bkv;
  const int lda = 1408;
  const int ldb = m0 ? 768 : 512;
  const int K   = m0 ? 768 : 512;
  const int gx  = m0 ? 12 : 16;
  const int nwg = m0 ? 192 : 256;
  const int lin0 = m0 ? id : id - 192;
  const int cpx = nwg >> 3;
  const int swzb = (lin0 & 7) * cpx + (lin0 >> 3);
  const long bm = (long)(swzb / gx) * 256;
  const long bn = (long)(swzb % gx) * 256;

  long aoff[2], boff[2];
#pragma unroll
  for (int j = 0; j < 2; ++j) {
    int lb = (j * 512 + tid) * 16;
    int swz = lb ^ (((lb >> 7) & 7) << 4);
    int sr = swz >> 7, sc = (swz & 127) >> 1;
    aoff[j] = (bm + sr) * (long)lda + sc;
    boff[j] = (bn + sr) * (long)ldb + sc;
  }

  auto STAGE = [&](int buf, int half, int isB, int tt) {
#pragma unroll
    for (int j = 0; j < 2; ++j) {
      const u16* src = isB ? (B + boff[j] + (long)half * 128 * ldb + tt * 64)
                           : (A + aoff[j] + (long)half * 128 * lda + tt * 64);
      __builtin_amdgcn_global_load_lds(
          (const GLV*)src,
          (LDSV*)((char*)SMEM + isB * 65536 + buf * 32768 + half * 16384 +
                  (j * 512 + tid) * 16),
          16, 0, 0);
    }
  };

  f32x4 acc[8][4] = {};
  bf16x8 a[4][2], b0[2][2], b1[2][2];

  auto LDA_ = [&](int buf, int qm) {
#pragma unroll
    for (int mf = 0; mf < 4; ++mf)
#pragma unroll
      for (int kk = 0; kk < 2; ++kk) {
        int r = mf * 32 + wm16 + l15;
        int lb = r * 128 + kk * 64 + l4 * 16;
        a[mf][kk] = *(const bf16x8*)((char*)SMEM + buf * 32768 + qm * 16384 +
                                     (lb ^ ((r & 7) << 4)));
      }
  };
  auto LDB_ = [&](int buf, int qn, bf16x8 (*bb)[2]) {
#pragma unroll
    for (int nf = 0; nf < 2; ++nf)
#pragma unroll
      for (int kk = 0; kk < 2; ++kk) {
        int r = nf * 64 + wn16 + l15;
        int lb = r * 128 + kk * 64 + l4 * 16;
        bb[nf][kk] = *(const bf16x8*)((char*)SMEM + 65536 + buf * 32768 +
                                      qn * 16384 + (lb ^ ((r & 7) << 4)));
      }
  };

  const int NT = K >> 6;
  STAGE(0, 0, 0, 0); STAGE(0, 0, 1, 0); STAGE(0, 1, 1, 0); STAGE(0, 1, 0, 0);
  STAGE(1, 0, 0, 1); STAGE(1, 0, 1, 1);
  asm volatile("s_waitcnt vmcnt(4)" ::: "memory");
  __builtin_amdgcn_s_barrier();

  for (int t = 0; t < NT; ++t) {
    const int cb = t & 1;
    if (t + 1 < NT) STAGE(cb ^ 1, 1, 1, t + 1);
    LDA_(cb, 0);
    LDB_(cb, 0, b0);
    __builtin_amdgcn_s_barrier();
    asm volatile("s_waitcnt lgkmcnt(0)" ::: "memory");
    __builtin_amdgcn_sched_barrier(0);
    MM_PHASE(0, 0, b0);
    __builtin_amdgcn_s_barrier();
    if (t + 1 < NT) STAGE(cb ^ 1, 1, 0, t + 1);
    LDB_(cb, 1, b1);
    __builtin_amdgcn_s_barrier();
    asm volatile("s_waitcnt lgkmcnt(0)" ::: "memory");
    __builtin_amdgcn_sched_barrier(0);
    MM_PHASE(0, 1, b1);
    __builtin_amdgcn_s_barrier();
    if (t + 2 < NT) STAGE(cb, 0, 0, t + 2);
    LDA_(cb, 1);
    __builtin_amdgcn_s_barrier();
    asm volatile("s_waitcnt lgkmcnt(0)" ::: "memory");
    __builtin_amdgcn_sched_barrier(0);
    MM_PHASE(1, 0, b0);
    __builtin_amdgcn_s_barrier();
    if (t + 2 < NT) STAGE(cb, 0, 1, t + 2);
    __builtin_amdgcn_s_barrier();
    MM_PHASE(1, 1, b1);
    if (t + 2 < NT) asm volatile("s_waitcnt vmcnt(4)" ::: "memory");
    else            asm volatile("s_waitcnt vmcnt(0)" ::: "memory");
    __builtin_amdgcn_s_barrier();
  }

#pragma unroll
  for (int mfg = 0; mfg < 8; ++mfg)
#pragma unroll
    for (int nfg = 0; nfg < 4; ++nfg)
#pragma unroll
      for (int r = 0; r < 4; ++r) {
        long row = bm + mfg * 32 + wm16 + l4 * 4 + r;
        long col = bn + nfg * 64 + wn16 + l15;
        float v = acc[mfg][nfg][r];
        if (m0) {
          Cq[row * 3072 + col] = f2bf(v);
        } else {
          int h = (int)(col >> 8), c = (int)(col & 255);
          if (c < 128)
            KbN[(((row >> 11) * 16 + h) * 2048 + (row & 2047)) * 128 + c] = f2bf(v);
          else
            Vc[row * 2048 + h * 128 + (c - 128)] = f2bf(v);
        }
      }
}

// ---------------- 256x128 4-phase NT GEMM (tall variant, 96KB LDS) ----------------
#define MM_TALL(QM, QN, BB)                                                      \
  __builtin_amdgcn_s_setprio(1);                                                 \
  {                                                                              \
    _Pragma("unroll") for (int mf = 0; mf < 4; ++mf) {                           \
      _Pragma("unroll") for (int kk = 0; kk < 2; ++kk) {                         \
        acc[(QM) * 4 + mf][(QN)] = __builtin_amdgcn_mfma_f32_16x16x32_bf16(      \
            a[mf][kk], BB[kk], acc[(QM) * 4 + mf][(QN)], 0, 0, 0);               \
      }                                                                          \
    }                                                                            \
  }                                                                              \
  __builtin_amdgcn_s_setprio(0);

template <int MODE>
__global__ __launch_bounds__(512, 2) void gemm_tall(const u16* __restrict__ A, int lda,
                                                    const u16* __restrict__ B, int ldb,
                                                    void* __restrict__ Cv, int ldc,
                                                    u16* __restrict__ Vc, int K) {
  __shared__ u16 SMEM[49152];  // 96 KB: A 64KB | B 32KB
  const int tid = threadIdx.x;
  const int lane = tid & 63, wid = tid >> 6;
  const int l15 = lane & 15, l4 = lane >> 4;
  const int wm16 = (wid >> 2) * 16, wn16 = (wid & 3) * 16;

  const int gx = gridDim.x, nwg = gx * gridDim.y;
  int lin0 = blockIdx.y * gx + blockIdx.x;
  int cpx = nwg >> 3;
  int swzb = (lin0 & 7) * cpx + (lin0 >> 3);
  const long bm = (long)(swzb / gx) * 256;
  const long bn = (long)(swzb % gx) * 128;

  long aoff[2], boffv;
#pragma unroll
  for (int j = 0; j < 2; ++j) {
    int lb = (j * 512 + tid) * 16;
    int swz = lb ^ (((lb >> 7) & 7) << 4);
    aoff[j] = (bm + (swz >> 7)) * (long)lda + ((swz & 127) >> 1);
  }
  {
    int lb = tid * 16;
    int swz = lb ^ (((lb >> 7) & 7) << 4);
    boffv = (bn + (swz >> 7)) * (long)ldb + ((swz & 127) >> 1);
  }

  auto SA = [&](int buf, int half, int tt) {
#pragma unroll
    for (int j = 0; j < 2; ++j)
      __builtin_amdgcn_global_load_lds(
          (const GLV*)(A + aoff[j] + (long)half * 128 * lda + tt * 64),
          (LDSV*)((char*)SMEM + buf * 32768 + half * 16384 + (j * 512 + tid) * 16),
          16, 0, 0);
  };
  auto SB = [&](int buf, int half, int tt) {
    __builtin_amdgcn_global_load_lds(
        (const GLV*)(B + boffv + (long)half * 64 * ldb + tt * 64),
        (LDSV*)((char*)SMEM + 65536 + buf * 16384 + half * 8192 + tid * 16),
        16, 0, 0);
  };

  f32x4 acc[8][2] = {};
  bf16x8 a[4][2], b0[2], b1[2];

  auto LDA_ = [&](int buf, int qm) {
#pragma unroll
    for (int mf = 0; mf < 4; ++mf)
#pragma unroll
      for (int kk = 0; kk < 2; ++kk) {
        int r = mf * 32 + wm16 + l15;
        int lb = r * 128 + kk * 64 + l4 * 16;
        a[mf][kk] = *(const bf16x8*)((char*)SMEM + buf * 32768 + qm * 16384 +
                                     (lb ^ ((r & 7) << 4)));
      }
  };
  auto LDB_ = [&](int buf, int qn, bf16x8* bb) {
#pragma unroll
    for (int kk = 0; kk < 2; ++kk) {
      int r = wn16 + l15;
      int lb = r * 128 + kk * 64 + l4 * 16;
      bb[kk] = *(const bf16x8*)((char*)SMEM + 65536 + buf * 16384 + qn * 8192 +
                                (lb ^ ((r & 7) << 4)));
    }
  };

  const int NT = K >> 6;
  SA(0, 0, 0); SB(0, 0, 0); SB(0, 1, 0); SA(0, 1, 0);
  SA(1, 0, 1); SB(1, 0, 1);
  asm volatile("s_waitcnt vmcnt(3)" ::: "memory");
  __builtin_amdgcn_s_barrier();

  for (int t = 0; t < NT; ++t) {
    const int cb = t & 1;
    if (t + 1 < NT) SB(cb ^ 1, 1, t + 1);
    LDA_(cb, 0);
    LDB_(cb, 0, b0);
    __builtin_amdgcn_s_barrier();
    asm volatile("s_waitcnt lgkmcnt(0)" ::: "memory");
    __builtin_amdgcn_sched_barrier(0);
    MM_TALL(0, 0, b0);
    __builtin_amdgcn_s_barrier();
    if (t + 1 < NT) SA(cb ^ 1, 1, t + 1);
    LDB_(cb, 1, b1);
    __builtin_amdgcn_s_barrier();
    asm volatile("s_waitcnt lgkmcnt(0)" ::: "memory");
    __builtin_amdgcn_sched_barrier(0);
    MM_TALL(0, 1, b1);
    __builtin_amdgcn_s_barrier();
    if (t + 2 < NT) SA(cb, 0, t + 2);
    LDA_(cb, 1);
    __builtin_amdgcn_s_barrier();
    asm volatile("s_waitcnt lgkmcnt(0)" ::: "memory");
    __builtin_amdgcn_sched_barrier(0);
    MM_TALL(1, 0, b0);
    __builtin_amdgcn_s_barrier();
    if (t + 2 < NT) SB(cb, 0, t + 2);
    __builtin_amdgcn_s_barrier();
    MM_TALL(1, 1, b1);
    if (t + 2 < NT) asm volatile("s_waitcnt vmcnt(6)" ::: "memory");
    else            asm volatile("s_waitcnt vmcnt(0)" ::: "memory");
    __builtin_amdgcn_s_barrier();
  }

#pragma unroll
  for (int mfg = 0; mfg < 8; ++mfg)
#pragma unroll
    for (int qn = 0; qn < 2; ++qn)
#pragma unroll
      for (int r = 0; r < 4; ++r) {
        long row = bm + mfg * 32 + wm16 + l4 * 4 + r;
        long col = bn + qn * 64 + wn16 + l15;
        float v = acc[mfg][qn][r];
        if constexpr (MODE == 0) {
          ((u16*)Cv)[row * ldc + col] = f2bf(v);
        } else {
          ((float*)Cv)[row * ldc + col] = v;
        }
      }
}

// ---------------- both RMSNorms + fused k_pe RoPE in one dispatch ----------------
__global__ __launch_bounds__(256) void rmsnorm2_kernel(u16* __restrict__ qakv,
                                                       const float* __restrict__ qw,
                                                       const float* __restrict__ kvw,
                                                       const float* __restrict__ cosb,
                                                       const float* __restrict__ sinb,
                                                       u16* __restrict__ kpe) {
  __shared__ float sred[4];
  const int tid = threadIdx.x;
  const int row = blockIdx.x;
  if (row < 4096) {
    u16* p = qakv + (size_t)row * 1408;
    float x[3];
    float ss = 0.f;
#pragma unroll
    for (int i = 0; i < 3; ++i) { x[i] = bf2f(p[tid + i * 256]); ss += x[i] * x[i]; }
#pragma unroll
    for (int off = 1; off < 64; off <<= 1) ss += __shfl_xor(ss, off);
    if ((tid & 63) == 0) sred[tid >> 6] = ss;
    __syncthreads();
    float tot = sred[0] + sred[1] + sred[2] + sred[3];
    float rs = rsqrtf(tot * (1.0f / 768.0f) + 1e-6f) * 0.0069411711f;  // SCALE*log2e/15
#pragma unroll
    for (int i = 0; i < 3; ++i) p[tid + i * 256] = f2bf(x[i] * rs * qw[tid + i * 256]);
  } else {
    const int srow = row - 4096;
    u16* p = qakv + (size_t)srow * 1408 + 768;
    float x[2];
    float ss = 0.f;
#pragma unroll
    for (int i = 0; i < 2; ++i) { x[i] = bf2f(p[tid + i * 256]); ss += x[i] * x[i]; }
#pragma unroll
    for (int off = 1; off < 64; off <<= 1) ss += __shfl_xor(ss, off);
    if ((tid & 63) == 0) sred[tid >> 6] = ss;
    __syncthreads();
    float tot = sred[0] + sred[1] + sred[2] + sred[3];
    float rs = rsqrtf(tot * (1.0f / 512.0f) + 1e-6f);
#pragma unroll
    for (int i = 0; i < 2; ++i) p[tid + i * 256] = f2bf(x[i] * rs * kvw[tid + i * 256]);
    // fused k_pe RoPE (cols 1280..1343) -> compact kpe [b*S][64]
    if (tid < 32) {
      int s = srow & 2047;
      unsigned int v = *(const unsigned int*)(qakv + (size_t)srow * 1408 + 1280 + 2 * tid);
      float xe = bf2f((u16)(v & 0xffff)), xo = bf2f((u16)(v >> 16));
      float c = cosb[s * 32 + tid], sn = sinb[s * 32 + tid];
      *(unsigned int*)(kpe + (size_t)srow * 64 + 2 * tid) =
          (unsigned int)f2bf(xe * c - xo * sn) | ((unsigned int)f2bf(xe * sn + xo * c) << 16);
    }
  }
}

// ---------------- fused causal attention + softcap + v-projection removal ----------
// 8 waves, QT=128, KT=64, reg-staged double-buffered K/V LDS -> ONE barrier per
// k-tile; global prefetch issued two tiles ahead. V transposed IN-STAGING from
// compact Vc (scalar b16 scatter, bank-spread swizzle c^= (d&7)^((d>>3)&7)).
// RoPE on Q at fragment load. Fixed softmax ref m=30. Paired q-tiles. XCD swizzle.
__global__ __launch_bounds__(512, 2) void attn_kernel(const u16* __restrict__ Qg,
                                                      const u16* __restrict__ KbN,
                                                      const u16* __restrict__ Kpe,
                                                      const u16* __restrict__ Vcg,
                                                      const float* __restrict__ cosb,
                                                      const float* __restrict__ sinb,
                                                      const float* __restrict__ gain,
                                                      u16* __restrict__ Yg) {
  __shared__ u16 Ks[2][64 * 192];   // 48KB
  __shared__ u16 VTs[2][128 * 64];  // 32KB  [d][t], swizzled
  __shared__ u16 Ps[128 * 64];      // 16KB (wave-private rows)

  const int tid = threadIdx.x, lane = tid & 63, wid = tid >> 6;
  const int l15 = lane & 15, l4 = lane >> 4;

  const int p = blockIdx.x;               // 256 blocks
  const int bh = (p & 7) * 4 + (p >> 6);  // same-bh blocks share an XCD
  const int pair = (p >> 3) & 7;
  const int b = bh >> 4, h = bh & 15;

  const u16* Kn = KbN + (long)bh * S_LEN * 128;
  const u16* Kp = Kpe + (long)b * S_LEN * 64;
  const u16* Vcb = Vcg + ((long)b * S_LEN) * 2048 + h * 128;  // + (k0+t)*2048 + dc*8

  int krow[3], sst[3], ksoff[3];
  const u16* sb[3];
#pragma unroll
  for (int i = 0; i < 3; ++i) {
    int flat = i * 512 + tid;
    int r = flat / 24, c = flat % 24;
    krow[i] = r;
    if (c < 16) { sb[i] = Kn + c * 8; sst[i] = 128; }
    else        { sb[i] = Kp + (c - 16) * 8; sst[i] = 64; }
    ksoff[i] = r * 192 + ((c ^ (r & 7)) * 8);
  }
  // V staging: chunk = (t, dc): flat = t*16 + dc; load Vc row t, 8 d's; scatter to
  // VTs[d][t] with swizzle. Precompute A0 = dc*512 + (t&7), s0 = (t>>3)^(dc&7).
  int vt_[2], vdc[2], vA0[2], vs0[2];
#pragma unroll
  for (int i = 0; i < 2; ++i) {
    int flat = i * 512 + tid;
    int t = flat >> 4, dc = flat & 15;
    vt_[i] = t; vdc[i] = dc;
    vA0[i] = dc * 512 + (t & 7);
    vs0[i] = (t >> 3) ^ (dc & 7);
  }

  const int prow = wid * 16 + l15;
  const int pr7 = prow & 7;
  const float g = gain[h];

  for (int seg = 0; seg < 2; ++seg) {
    const int qt = seg ? pair : 15 - pair;
    const int q0 = qt * 128;
    const int nkt = 2 * qt + 2;
    const int sq = q0 + prow;

    bf16x8 qf[6];
    {
      const u16* qb_ = Qg + ((long)b * S_LEN + sq) * 3072 + h * 192;
#pragma unroll
      for (int f = 0; f < 6; ++f) qf[f] = *(const bf16x8*)(qb_ + f * 32 + 8 * l4);
    }
    // RoPE + gain on q_pe fragments (f=4,5): pairs are in-lane
#pragma unroll
    for (int f = 4; f < 6; ++f) {
      float4 cv = *(const float4*)(cosb + sq * 32 + (f - 4) * 16 + l4 * 4);
      float4 sv = *(const float4*)(sinb + sq * 32 + (f - 4) * 16 + l4 * 4);
      float cc[4] = {cv.x, cv.y, cv.z, cv.w};
      float ssn[4] = {sv.x, sv.y, sv.z, sv.w};
      u16* pq = (u16*)&qf[f];
#pragma unroll
      for (int pp = 0; pp < 4; ++pp) {
        float xe = bf2f(pq[2 * pp]), xo = bf2f(pq[2 * pp + 1]);
        pq[2 * pp]     = f2bf((xe * cc[pp] - xo * ssn[pp]) * g);
        pq[2 * pp + 1] = f2bf((xe * ssn[pp] + xo * cc[pp]) * g);
      }
    }

    f32x4 o[8] = {};
    float lsum = 0.f;

    u32x4 ka[3], va[2];
    auto VWRITE = [&](int buf) {
#pragma unroll
      for (int i = 0; i < 2; ++i) {
        const u16* pv = (const u16*)&va[i];
#pragma unroll
        for (int j = 0; j < 8; ++j)
          VTs[buf][vA0[i] + j * 64 + ((vs0[i] ^ j) << 3)] = pv[j];
      }
    };
    // prologue: tile 0 -> LDS[0]; prefetch tile 1 into regs
#pragma unroll
    for (int i = 0; i < 3; ++i)
      ka[i] = *(const u32x4*)(sb[i] + (long)krow[i] * sst[i]);
#pragma unroll
    for (int i = 0; i < 2; ++i)
      va[i] = *(const u32x4*)(Vcb + (long)vt_[i] * 2048 + vdc[i] * 8);
#pragma unroll
    for (int i = 0; i < 3; ++i) *(u32x4*)(&Ks[0][ksoff[i]]) = ka[i];
    VWRITE(0);
    if (nkt > 1) {
#pragma unroll
      for (int i = 0; i < 3; ++i)
        ka[i] = *(const u32x4*)(sb[i] + (long)(64 + krow[i]) * sst[i]);
#pragma unroll
      for (int i = 0; i < 2; ++i)
        va[i] = *(const u32x4*)(Vcb + (long)(64 + vt_[i]) * 2048 + vdc[i] * 8);
    }
    __syncthreads();

    for (int it = 0; it < nkt; ++it) {
      const int cur = it & 1;

      f32x4 sacc[4] = {};
      __builtin_amdgcn_s_setprio(1);
#pragma unroll
      for (int f = 0; f < 6; ++f)
#pragma unroll
        for (int tf = 0; tf < 4; ++tf) {
          int row = tf * 16 + l15;
          bf16x8 kf = *(const bf16x8*)(&Ks[cur][row * 192 + (((f * 4 + l4) ^ (row & 7)) * 8)]);
          sacc[tf] = __builtin_amdgcn_mfma_f32_16x16x32_bf16(kf, qf[f], sacc[tf], 0, 0, 0);
        }
      __builtin_amdgcn_s_setprio(0);

      // stage next tile into other buffer; prefetch t+2 into regs
      if (it + 1 < nkt) {
#pragma unroll
        for (int i = 0; i < 3; ++i) *(u32x4*)(&Ks[cur ^ 1][ksoff[i]]) = ka[i];
        VWRITE(cur ^ 1);
      }
      if (it + 2 < nkt) {
        int k0n = (it + 2) * 64;
#pragma unroll
        for (int i = 0; i < 3; ++i)
          ka[i] = *(const u32x4*)(sb[i] + (long)(k0n + krow[i]) * sst[i]);
#pragma unroll
        for (int i = 0; i < 2; ++i)
          va[i] = *(const u32x4*)(Vcb + (long)(k0n + vt_[i]) * 2048 + vdc[i] * 8);
      }

      // softmax with fixed reference (q pre-scaled in rmsnorm)
#pragma unroll
      for (int tf = 0; tf < 4; ++tf)
#pragma unroll
        for (int r = 0; r < 4; ++r) {
          float u = __builtin_amdgcn_exp2f(sacc[tf][r]);
          sacc[tf][r] = __builtin_amdgcn_exp2f(-86.56170245333781f *
                                               __builtin_amdgcn_rcpf(u + 1.0f));
        }
      if (it * 64 >= q0) {  // causal: kpos > qrow -> 0
        const int dthr = q0 + prow - it * 64 - l4 * 4;
#pragma unroll
        for (int tf = 0; tf < 4; ++tf)
#pragma unroll
          for (int r = 0; r < 4; ++r)
            if (tf * 16 + r > dthr) sacc[tf][r] = 0.f;
      }
#pragma unroll
      for (int tf = 0; tf < 4; ++tf)
#pragma unroll
        for (int r = 0; r < 4; ++r) lsum += sacc[tf][r];

#pragma unroll
      for (int tf = 0; tf < 4; ++tf) {
        u32x2 w;
        w.x = cvtpk(sacc[tf][0], sacc[tf][1]);
        w.y = cvtpk(sacc[tf][2], sacc[tf][3]);
        int chunk = tf * 2 + (l4 >> 1);
        *(u32x2*)(&Ps[prow * 64 + ((chunk ^ pr7) * 8) + (l4 & 1) * 4]) = w;
      }

      __builtin_amdgcn_s_setprio(1);
#pragma unroll
      for (int kk = 0; kk < 2; ++kk) {
        bf16x8 pf = *(const bf16x8*)(&Ps[prow * 64 + (((kk * 4 + l4) ^ pr7) * 8)]);
#pragma unroll
        for (int nf = 0; nf < 8; ++nf) {
          int vr = nf * 16 + l15;
          int cc = (kk * 4 + l4) ^ (vr & 7) ^ ((vr >> 3) & 7);
          bf16x8 vf = *(const bf16x8*)(&VTs[cur][vr * 64 + cc * 8]);
          o[nf] = __builtin_amdgcn_mfma_f32_16x16x32_bf16(pf, vf, o[nf], 0, 0, 0);
        }
      }
      __builtin_amdgcn_s_setprio(0);

      __syncthreads();  // single barrier per tile: flip buffers
    }

    lsum += __shfl_xor(lsum, 16);
    lsum += __shfl_xor(lsum, 32);
    float inv[4];
#pragma unroll
    for (int r = 0; r < 4; ++r)
      inv[r] = __builtin_amdgcn_rcpf(__shfl(lsum, l4 * 4 + r));

    float yv[8][4], vvv[8][4];
    float ssum[4] = {0.f, 0.f, 0.f, 0.f}, dsum[4] = {0.f, 0.f, 0.f, 0.f};
    const u16* vb = Vcg + ((long)b * S_LEN + q0 + wid * 16) * 2048 + h * 128;
#pragma unroll
    for (int nf = 0; nf < 8; ++nf)
#pragma unroll
      for (int r = 0; r < 4; ++r) {
        float vv = bf2f(vb[(l4 * 4 + r) * 2048 + nf * 16 + l15]);
        float y = o[nf][r] * inv[r];
        vvv[nf][r] = vv; yv[nf][r] = y;
        ssum[r] += vv * vv; dsum[r] += y * vv;
      }
#pragma unroll
    for (int r = 0; r < 4; ++r) {
      ssum[r] += __shfl_xor(ssum[r], 1); ssum[r] += __shfl_xor(ssum[r], 2);
      ssum[r] += __shfl_xor(ssum[r], 4); ssum[r] += __shfl_xor(ssum[r], 8);
      dsum[r] += __shfl_xor(dsum[r], 1); dsum[r] += __shfl_xor(dsum[r], 2);
      dsum[r] += __shfl_xor(dsum[r], 4); dsum[r] += __shfl_xor(dsum[r], 8);
      dsum[r] *= __builtin_amdgcn_rcpf(fmaxf(ssum[r], 1e-12f));
    }
#pragma unroll
    for (int nf = 0; nf < 8; ++nf)
#pragma unroll
      for (int r = 0; r < 4; ++r) {
        long row = (long)b * S_LEN + q0 + wid * 16 + l4 * 4 + r;
        Yg[row * 2048 + h * 128 + nf * 16 + l15] = f2bf(yv[nf][r] - dsum[r] * vvv[nf][r]);
      }
  }
}

extern "C" void kernel_launch(void* const* d_in, const int* in_sizes, int n_in,
                              void* d_out, int out_size, void* d_ws, size_t ws_size,
                              hipStream_t stream) {
  const float* x       = (const float*)d_in[0];
  const float* wq_a    = (const float*)d_in[1];
  const float* q_norm  = (const float*)d_in[2];
  const float* wq_b    = (const float*)d_in[3];
  const float* q_gain  = (const float*)d_in[4];
  const float* wkv_a   = (const float*)d_in[5];
  const float* kv_norm = (const float*)d_in[6];
  const float* wkv_b   = (const float*)d_in[7];
  const float* wo      = (const float*)d_in[8];
  const float* fcos    = (const float*)d_in[9];
  const float* fsin    = (const float*)d_in[10];
  float* out = (float*)d_out;

  char* ws = (char*)d_ws;
  size_t off = 0;
  auto alloc = [&](size_t bytes) {
    char* pp = ws + off;
    off += (bytes + 255) & ~(size_t)255;
    return pp;
  };
  const long M = 4096;  // B*S
  u16* xb    = (u16*)alloc(M * 2048 * 2);
  u16* wcomb = (u16*)alloc(1408L * 2048 * 2);
  u16* wqbb  = (u16*)alloc(3072L * 768 * 2);
  u16* wkvbb = (u16*)alloc(4096L * 512 * 2);
  u16* wob   = (u16*)alloc(2048L * 2048 * 2);
  u16* qakv  = (u16*)alloc(M * 1408 * 2);
  u16* qb    = (u16*)alloc(M * 3072 * 2);
  u16* KbN   = (u16*)alloc(32L * 2048 * 128 * 2);
  u16* kpe   = (u16*)alloc(M * 64 * 2);
  u16* Vc    = (u16*)alloc(M * 2048 * 2);
  u16* Yb    = (u16*)alloc(M * 2048 * 2);

  const long n4_x = 2097152, n4_wqa = 393216, n4_wqb = 589824,
             n4_wkvb = 524288, n4_wo = 1048576, n4_wkvap = 327680;
  long e0 = n4_x, e1 = e0 + n4_wqa, e2 = e1 + n4_wqb, e3 = e2 + n4_wkvb,
       e4 = e3 + n4_wo, e5 = e4 + n4_wkvap;
  cast_all<<<(int)(e5 / 256), 256, 0, stream>>>(
      x, xb, e0, wq_a, wcomb, e1, wq_b, wqbb, e2, wkv_b, wkvbb, e3,
      wo, wob, e4, wkv_a, wcomb + 768L * 2048, e5);

  // fused: [q_a | kv_full] = x @ [wq_a; wkv_a]^T   (N=1408, 256x128 tall)
  gemm_tall<0><<<dim3(11, 16), 512, 0, stream>>>(xb, 2048, wcomb, 2048, qakv, 1408, nullptr, 2048);
  rmsnorm2_kernel<<<8192, 256, 0, stream>>>(qakv, q_norm, kv_norm, fcos, fsin, kpe);
  // GEMM2 (q-proj) + GEMM4 (kv-proj split) fused in one 448-block dispatch
  gemm256_dual<<<448, 512, 0, stream>>>(qakv, wqbb, qb, qakv + 768, wkvbb, KbN, Vc);
  attn_kernel<<<256, 512, 0, stream>>>(qb, KbN, kpe, Vc, fcos, fsin, q_gain, Yb);
  // out = y @ wo^T (f32 out)  (256x128 tall)
  gemm_tall<1><<<dim3(16, 16), 512, 0, stream>>>(Yb, 2048, wob, 2048, out, 2048, nullptr, 2048);
}

// Round 17
// 234.325 us; speedup vs baseline: 1.0550x; 1.0550x over previous
//
#include <hip/hip_runtime.h>
#include <stdint.h>

typedef unsigned short u16;
typedef __bf16 bf16x8 __attribute__((ext_vector_type(8)));
typedef float f32x4 __attribute__((ext_vector_type(4)));
typedef unsigned int u32x4 __attribute__((ext_vector_type(4)));
typedef unsigned int u32x2 __attribute__((ext_vector_type(2)));

typedef __attribute__((address_space(3))) void LDSV;
typedef __attribute__((address_space(1))) void GLV;

#define S_LEN 2048

__device__ __forceinline__ float bf2f(u16 u) {
  union { unsigned int i; float f; } v; v.i = ((unsigned int)u) << 16; return v.f;
}
__device__ __forceinline__ u16 f2bf(float f) {
  union { float f; unsigned int i; } v; v.f = f;
  unsigned int x = v.i;
  return (u16)((x + 0x7fffu + ((x >> 16) & 1u)) >> 16);
}
__device__ __forceinline__ unsigned int cvtpk(float lo, float hi) {
  unsigned int r;
  asm("v_cvt_pk_bf16_f32 %0, %1, %2" : "=v"(r) : "v"(lo), "v"(hi));
  return r;
}
__device__ __forceinline__ unsigned long long pack4(float4 v) {
  return (unsigned long long)f2bf(v.x)
       | ((unsigned long long)f2bf(v.y) << 16)
       | ((unsigned long long)f2bf(v.z) << 32)
       | ((unsigned long long)f2bf(v.w) << 48);
}

// ---------------- all casts in one dispatch ----------------
__global__ __launch_bounds__(256) void cast_all(
    const float* __restrict__ s0, u16* __restrict__ d0, long e0,
    const float* __restrict__ s1, u16* __restrict__ d1, long e1,
    const float* __restrict__ s2, u16* __restrict__ d2, long e2,
    const float* __restrict__ s3, u16* __restrict__ d3, long e3,
    const float* __restrict__ s4, u16* __restrict__ d4, long e4,
    const float* __restrict__ s5, u16* __restrict__ d5, long e5) {
  long i = (long)blockIdx.x * 256 + threadIdx.x;
  const float* src; u16* dst; long base; bool pad = false;
  if (i < e0)      { src = s0; dst = d0; base = 0; }
  else if (i < e1) { src = s1; dst = d1; base = e0; }
  else if (i < e2) { src = s2; dst = d2; base = e1; }
  else if (i < e3) { src = s3; dst = d3; base = e2; }
  else if (i < e4) { src = s4; dst = d4; base = e3; }
  else if (i < e5) { src = s5; dst = d5; base = e4; pad = true; }
  else return;
  long li = i - base;
  long elem0 = li * 4;
  unsigned long long r = 0;
  if (!pad || (elem0 >> 11) < 576)
    r = pack4(*(const float4*)(src + elem0));
  ((unsigned long long*)dst)[li] = r;
}

// ---------------- dual 256x256 8-phase NT GEMM (GEMM2 + GEMM4 in one grid) --------
#define MM_PHASE(QM, QN, BB)                                                     \
  __builtin_amdgcn_s_setprio(1);                                                 \
  {                                                                              \
    _Pragma("unroll") for (int mf = 0; mf < 4; ++mf) {                           \
      _Pragma("unroll") for (int nf = 0; nf < 2; ++nf) {                         \
        _Pragma("unroll") for (int kk = 0; kk < 2; ++kk) {                       \
          acc[(QM) * 4 + mf][(QN) * 2 + nf] =                                    \
              __builtin_amdgcn_mfma_f32_16x16x32_bf16(                           \
                  a[mf][kk], BB[nf][kk], acc[(QM) * 4 + mf][(QN) * 2 + nf],      \
                  0, 0, 0);                                                      \
        }                                                                        \
      }                                                                          \
    }                                                                            \
  }                                                                              \
  __builtin_amdgcn_s_setprio(0);

__global__ __launch_bounds__(512, 2) void gemm256_dual(const u16* __restrict__ Aq,
                                                       const u16* __restrict__ Bq,
                                                       u16* __restrict__ Cq,
                                                       const u16* __restrict__ Akv,
                                                       const u16* __restrict__ Bkv,
                                                       u16* __restrict__ KbN,
                                                       u16* __restrict__ Vc) {
  __shared__ u16 SMEM[65536];  // 128 KB
  const int tid = threadIdx.x;
  const int lane = tid & 63, wid = tid >> 6;
  const int l15 = lane & 15, l4 = lane >> 4;
  const int wm16 = (wid >> 2) * 16, wn16 = (wid & 3) * 16;

  const int id = blockIdx.x;
  const bool m0 = (id < 192);
  const u16* A = m0 ? Aq : Akv;
  const u16* B = m0 ? Bq : Bkv;
  const int lda = 1408;
  const int ldb = m0 ? 768 : 512;
  const int K   = m0 ? 768 : 512;
  const int gx  = m0 ? 12 : 16;
  const int nwg = m0 ? 192 : 256;
  const int lin0 = m0 ? id : id - 192;
  const int cpx = nwg >> 3;
  const int swzb = (lin0 & 7) * cpx + (lin0 >> 3);
  const long bm = (long)(swzb / gx) * 256;
  const long bn = (long)(swzb % gx) * 256;

  long aoff[2], boff[2];
#pragma unroll
  for (int j = 0; j < 2; ++j) {
    int lb = (j * 512 + tid) * 16;
    int swz = lb ^ (((lb >> 7) & 7) << 4);
    int sr = swz >> 7, sc = (swz & 127) >> 1;
    aoff[j] = (bm + sr) * (long)lda + sc;
    boff[j] = (bn + sr) * (long)ldb + sc;
  }

  auto STAGE = [&](int buf, int half, int isB, int tt) {
#pragma unroll
    for (int j = 0; j < 2; ++j) {
      const u16* src = isB ? (B + boff[j] + (long)half * 128 * ldb + tt * 64)
                           : (A + aoff[j] + (long)half * 128 * lda + tt * 64);
      __builtin_amdgcn_global_load_lds(
          (const GLV*)src,
          (LDSV*)((char*)SMEM + isB * 65536 + buf * 32768 + half * 16384 +
                  (j * 512 + tid) * 16),
          16, 0, 0);
    }
  };

  f32x4 acc[8][4] = {};
  bf16x8 a[4][2], b0[2][2], b1[2][2];

  auto LDA_ = [&](int buf, int qm) {
#pragma unroll
    for (int mf = 0; mf < 4; ++mf)
#pragma unroll
      for (int kk = 0; kk < 2; ++kk) {
        int r = mf * 32 + wm16 + l15;
        int lb = r * 128 + kk * 64 + l4 * 16;
        a[mf][kk] = *(const bf16x8*)((char*)SMEM + buf * 32768 + qm * 16384 +
                                     (lb ^ ((r & 7) << 4)));
      }
  };
  auto LDB_ = [&](int buf, int qn, bf16x8 (*bb)[2]) {
#pragma unroll
    for (int nf = 0; nf < 2; ++nf)
#pragma unroll
      for (int kk = 0; kk < 2; ++kk) {
        int r = nf * 64 + wn16 + l15;
        int lb = r * 128 + kk * 64 + l4 * 16;
        bb[nf][kk] = *(const bf16x8*)((char*)SMEM + 65536 + buf * 32768 +
                                      qn * 16384 + (lb ^ ((r & 7) << 4)));
      }
  };

  const int NT = K >> 6;
  STAGE(0, 0, 0, 0); STAGE(0, 0, 1, 0); STAGE(0, 1, 1, 0); STAGE(0, 1, 0, 0);
  STAGE(1, 0, 0, 1); STAGE(1, 0, 1, 1);
  asm volatile("s_waitcnt vmcnt(4)" ::: "memory");
  __builtin_amdgcn_s_barrier();

  for (int t = 0; t < NT; ++t) {
    const int cb = t & 1;
    if (t + 1 < NT) STAGE(cb ^ 1, 1, 1, t + 1);
    LDA_(cb, 0);
    LDB_(cb, 0, b0);
    __builtin_amdgcn_s_barrier();
    asm volatile("s_waitcnt lgkmcnt(0)" ::: "memory");
    __builtin_amdgcn_sched_barrier(0);
    MM_PHASE(0, 0, b0);
    __builtin_amdgcn_s_barrier();
    if (t + 1 < NT) STAGE(cb ^ 1, 1, 0, t + 1);
    LDB_(cb, 1, b1);
    __builtin_amdgcn_s_barrier();
    asm volatile("s_waitcnt lgkmcnt(0)" ::: "memory");
    __builtin_amdgcn_sched_barrier(0);
    MM_PHASE(0, 1, b1);
    __builtin_amdgcn_s_barrier();
    if (t + 2 < NT) STAGE(cb, 0, 0, t + 2);
    LDA_(cb, 1);
    __builtin_amdgcn_s_barrier();
    asm volatile("s_waitcnt lgkmcnt(0)" ::: "memory");
    __builtin_amdgcn_sched_barrier(0);
    MM_PHASE(1, 0, b0);
    __builtin_amdgcn_s_barrier();
    if (t + 2 < NT) STAGE(cb, 0, 1, t + 2);
    __builtin_amdgcn_s_barrier();
    MM_PHASE(1, 1, b1);
    if (t + 2 < NT) asm volatile("s_waitcnt vmcnt(4)" ::: "memory");
    else            asm volatile("s_waitcnt vmcnt(0)" ::: "memory");
    __builtin_amdgcn_s_barrier();
  }

#pragma unroll
  for (int mfg = 0; mfg < 8; ++mfg)
#pragma unroll
    for (int nfg = 0; nfg < 4; ++nfg)
#pragma unroll
      for (int r = 0; r < 4; ++r) {
        long row = bm + mfg * 32 + wm16 + l4 * 4 + r;
        long col = bn + nfg * 64 + wn16 + l15;
        float v = acc[mfg][nfg][r];
        if (m0) {
          Cq[row * 3072 + col] = f2bf(v);
        } else {
          int h = (int)(col >> 8), c = (int)(col & 255);
          if (c < 128)
            KbN[(((row >> 11) * 16 + h) * 2048 + (row & 2047)) * 128 + c] = f2bf(v);
          else
            Vc[row * 2048 + h * 128 + (c - 128)] = f2bf(v);
        }
      }
}

// ---------------- 256x128 4-phase NT GEMM (tall variant, 96KB LDS) ----------------
#define MM_TALL(QM, QN, BB)                                                      \
  __builtin_amdgcn_s_setprio(1);                                                 \
  {                                                                              \
    _Pragma("unroll") for (int mf = 0; mf < 4; ++mf) {                           \
      _Pragma("unroll") for (int kk = 0; kk < 2; ++kk) {                         \
        acc[(QM) * 4 + mf][(QN)] = __builtin_amdgcn_mfma_f32_16x16x32_bf16(      \
            a[mf][kk], BB[kk], acc[(QM) * 4 + mf][(QN)], 0, 0, 0);               \
      }                                                                          \
    }                                                                            \
  }                                                                              \
  __builtin_amdgcn_s_setprio(0);

template <int MODE>
__global__ __launch_bounds__(512, 2) void gemm_tall(const u16* __restrict__ A, int lda,
                                                    const u16* __restrict__ B, int ldb,
                                                    void* __restrict__ Cv, int ldc,
                                                    u16* __restrict__ Vc, int K) {
  __shared__ u16 SMEM[49152];  // 96 KB: A 64KB | B 32KB
  const int tid = threadIdx.x;
  const int lane = tid & 63, wid = tid >> 6;
  const int l15 = lane & 15, l4 = lane >> 4;
  const int wm16 = (wid >> 2) * 16, wn16 = (wid & 3) * 16;

  const int gx = gridDim.x, nwg = gx * gridDim.y;
  int lin0 = blockIdx.y * gx + blockIdx.x;
  int cpx = nwg >> 3;
  int swzb = (lin0 & 7) * cpx + (lin0 >> 3);
  const long bm = (long)(swzb / gx) * 256;
  const long bn = (long)(swzb % gx) * 128;

  long aoff[2], boffv;
#pragma unroll
  for (int j = 0; j < 2; ++j) {
    int lb = (j * 512 + tid) * 16;
    int swz = lb ^ (((lb >> 7) & 7) << 4);
    aoff[j] = (bm + (swz >> 7)) * (long)lda + ((swz & 127) >> 1);
  }
  {
    int lb = tid * 16;
    int swz = lb ^ (((lb >> 7) & 7) << 4);
    boffv = (bn + (swz >> 7)) * (long)ldb + ((swz & 127) >> 1);
  }

  auto SA = [&](int buf, int half, int tt) {
#pragma unroll
    for (int j = 0; j < 2; ++j)
      __builtin_amdgcn_global_load_lds(
          (const GLV*)(A + aoff[j] + (long)half * 128 * lda + tt * 64),
          (LDSV*)((char*)SMEM + buf * 32768 + half * 16384 + (j * 512 + tid) * 16),
          16, 0, 0);
  };
  auto SB = [&](int buf, int half, int tt) {
    __builtin_amdgcn_global_load_lds(
        (const GLV*)(B + boffv + (long)half * 64 * ldb + tt * 64),
        (LDSV*)((char*)SMEM + 65536 + buf * 16384 + half * 8192 + tid * 16),
        16, 0, 0);
  };

  f32x4 acc[8][2] = {};
  bf16x8 a[4][2], b0[2], b1[2];

  auto LDA_ = [&](int buf, int qm) {
#pragma unroll
    for (int mf = 0; mf < 4; ++mf)
#pragma unroll
      for (int kk = 0; kk < 2; ++kk) {
        int r = mf * 32 + wm16 + l15;
        int lb = r * 128 + kk * 64 + l4 * 16;
        a[mf][kk] = *(const bf16x8*)((char*)SMEM + buf * 32768 + qm * 16384 +
                                     (lb ^ ((r & 7) << 4)));
      }
  };
  auto LDB_ = [&](int buf, int qn, bf16x8* bb) {
#pragma unroll
    for (int kk = 0; kk < 2; ++kk) {
      int r = wn16 + l15;
      int lb = r * 128 + kk * 64 + l4 * 16;
      bb[kk] = *(const bf16x8*)((char*)SMEM + 65536 + buf * 16384 + qn * 8192 +
                                (lb ^ ((r & 7) << 4)));
    }
  };

  const int NT = K >> 6;
  SA(0, 0, 0); SB(0, 0, 0); SB(0, 1, 0); SA(0, 1, 0);
  SA(1, 0, 1); SB(1, 0, 1);
  asm volatile("s_waitcnt vmcnt(3)" ::: "memory");
  __builtin_amdgcn_s_barrier();

  for (int t = 0; t < NT; ++t) {
    const int cb = t & 1;
    if (t + 1 < NT) SB(cb ^ 1, 1, t + 1);
    LDA_(cb, 0);
    LDB_(cb, 0, b0);
    __builtin_amdgcn_s_barrier();
    asm volatile("s_waitcnt lgkmcnt(0)" ::: "memory");
    __builtin_amdgcn_sched_barrier(0);
    MM_TALL(0, 0, b0);
    __builtin_amdgcn_s_barrier();
    if (t + 1 < NT) SA(cb ^ 1, 1, t + 1);
    LDB_(cb, 1, b1);
    __builtin_amdgcn_s_barrier();
    asm volatile("s_waitcnt lgkmcnt(0)" ::: "memory");
    __builtin_amdgcn_sched_barrier(0);
    MM_TALL(0, 1, b1);
    __builtin_amdgcn_s_barrier();
    if (t + 2 < NT) SA(cb, 0, t + 2);
    LDA_(cb, 1);
    __builtin_amdgcn_s_barrier();
    asm volatile("s_waitcnt lgkmcnt(0)" ::: "memory");
    __builtin_amdgcn_sched_barrier(0);
    MM_TALL(1, 0, b0);
    __builtin_amdgcn_s_barrier();
    if (t + 2 < NT) SB(cb, 0, t + 2);
    __builtin_amdgcn_s_barrier();
    MM_TALL(1, 1, b1);
    if (t + 2 < NT) asm volatile("s_waitcnt vmcnt(6)" ::: "memory");
    else            asm volatile("s_waitcnt vmcnt(0)" ::: "memory");
    __builtin_amdgcn_s_barrier();
  }

#pragma unroll
  for (int mfg = 0; mfg < 8; ++mfg)
#pragma unroll
    for (int qn = 0; qn < 2; ++qn)
#pragma unroll
      for (int r = 0; r < 4; ++r) {
        long row = bm + mfg * 32 + wm16 + l4 * 4 + r;
        long col = bn + qn * 64 + wn16 + l15;
        float v = acc[mfg][qn][r];
        if constexpr (MODE == 0) {
          ((u16*)Cv)[row * ldc + col] = f2bf(v);
        } else {
          ((float*)Cv)[row * ldc + col] = v;
        }
      }
}

// ---------------- both RMSNorms + fused k_pe RoPE in one dispatch ----------------
__global__ __launch_bounds__(256) void rmsnorm2_kernel(u16* __restrict__ qakv,
                                                       const float* __restrict__ qw,
                                                       const float* __restrict__ kvw,
                                                       const float* __restrict__ cosb,
                                                       const float* __restrict__ sinb,
                                                       u16* __restrict__ kpe) {
  __shared__ float sred[4];
  const int tid = threadIdx.x;
  const int row = blockIdx.x;
  if (row < 4096) {
    u16* p = qakv + (size_t)row * 1408;
    float x[3];
    float ss = 0.f;
#pragma unroll
    for (int i = 0; i < 3; ++i) { x[i] = bf2f(p[tid + i * 256]); ss += x[i] * x[i]; }
#pragma unroll
    for (int off = 1; off < 64; off <<= 1) ss += __shfl_xor(ss, off);
    if ((tid & 63) == 0) sred[tid >> 6] = ss;
    __syncthreads();
    float tot = sred[0] + sred[1] + sred[2] + sred[3];
    float rs = rsqrtf(tot * (1.0f / 768.0f) + 1e-6f) * 0.0069411711f;  // SCALE*log2e/15
#pragma unroll
    for (int i = 0; i < 3; ++i) p[tid + i * 256] = f2bf(x[i] * rs * qw[tid + i * 256]);
  } else {
    const int srow = row - 4096;
    u16* p = qakv + (size_t)srow * 1408 + 768;
    float x[2];
    float ss = 0.f;
#pragma unroll
    for (int i = 0; i < 2; ++i) { x[i] = bf2f(p[tid + i * 256]); ss += x[i] * x[i]; }
#pragma unroll
    for (int off = 1; off < 64; off <<= 1) ss += __shfl_xor(ss, off);
    if ((tid & 63) == 0) sred[tid >> 6] = ss;
    __syncthreads();
    float tot = sred[0] + sred[1] + sred[2] + sred[3];
    float rs = rsqrtf(tot * (1.0f / 512.0f) + 1e-6f);
#pragma unroll
    for (int i = 0; i < 2; ++i) p[tid + i * 256] = f2bf(x[i] * rs * kvw[tid + i * 256]);
    // fused k_pe RoPE (cols 1280..1343) -> compact kpe [b*S][64]
    if (tid < 32) {
      int s = srow & 2047;
      unsigned int v = *(const unsigned int*)(qakv + (size_t)srow * 1408 + 1280 + 2 * tid);
      float xe = bf2f((u16)(v & 0xffff)), xo = bf2f((u16)(v >> 16));
      float c = cosb[s * 32 + tid], sn = sinb[s * 32 + tid];
      *(unsigned int*)(kpe + (size_t)srow * 64 + 2 * tid) =
          (unsigned int)f2bf(xe * c - xo * sn) | ((unsigned int)f2bf(xe * sn + xo * c) << 16);
    }
  }
}

// ---------------- V transpose: VT [B*H][128][S] from Vc [B*S][2048] ----------------
__global__ __launch_bounds__(256) void v_transpose_kernel(const u16* __restrict__ Vc,
                                                          u16* __restrict__ VT) {
  __shared__ u16 tile[64][65];
  int bh = blockIdx.z;
  int d0 = blockIdx.y * 64;
  int t0 = blockIdx.x * 64;
  int b = bh >> 4, h = bh & 15;
#pragma unroll
  for (int i = 0; i < 2; ++i) {
    int flat = i * 256 + threadIdx.x;
    int t = flat >> 3, c = (flat & 7) * 8;
    u32x4 v = *(const u32x4*)(Vc + ((long)b * S_LEN + t0 + t) * 2048 + h * 128 + d0 + c);
    const u16* pv = (const u16*)&v;
#pragma unroll
    for (int j = 0; j < 8; ++j) tile[c + j][t] = pv[j];
  }
  __syncthreads();
#pragma unroll
  for (int i = 0; i < 2; ++i) {
    int flat = i * 256 + threadIdx.x;
    int d = flat >> 3, tc = (flat & 7) * 8;
    u32x4 v;
    u16* pv = (u16*)&v;
#pragma unroll
    for (int j = 0; j < 8; ++j) pv[j] = tile[d][tc + j];
    *(u32x4*)(VT + ((long)bh * 128 + d0 + d) * S_LEN + t0 + tc) = v;
  }
}

// ---------------- fused causal attention + softcap + v-projection removal ----------
// 8 waves, QT=128, KT=64, reg-staged double-buffered K/V LDS -> ONE barrier per
// k-tile; global prefetch issued two tiles ahead. RoPE on Q at fragment load.
// Fixed softmax ref m=30. Paired q-tiles (qt,15-qt). XCD swizzle. Swapped QK.
__global__ __launch_bounds__(512, 2) void attn_kernel(const u16* __restrict__ Qg,
                                                      const u16* __restrict__ KbN,
                                                      const u16* __restrict__ Kpe,
                                                      const u16* __restrict__ VTg,
                                                      const u16* __restrict__ Vcg,
                                                      const float* __restrict__ cosb,
                                                      const float* __restrict__ sinb,
                                                      const float* __restrict__ gain,
                                                      u16* __restrict__ Yg) {
  __shared__ u16 Ks[2][64 * 192];   // 48KB
  __shared__ u16 VTs[2][128 * 64];  // 32KB
  __shared__ u16 Ps[128 * 64];      // 16KB (wave-private rows)

  const int tid = threadIdx.x, lane = tid & 63, wid = tid >> 6;
  const int l15 = lane & 15, l4 = lane >> 4;

  const int p = blockIdx.x;               // 256 blocks
  const int bh = (p & 7) * 4 + (p >> 6);  // same-bh blocks share an XCD
  const int pair = (p >> 3) & 7;
  const int b = bh >> 4, h = bh & 15;

  const u16* Kn = KbN + (long)bh * S_LEN * 128;
  const u16* Kp = Kpe + (long)b * S_LEN * 64;
  const u16* Vbh = VTg + (long)bh * 128 * S_LEN;

  int krow[3], sst[3], ksoff[3];
  const u16* sb[3];
#pragma unroll
  for (int i = 0; i < 3; ++i) {
    int flat = i * 512 + tid;
    int r = flat / 24, c = flat % 24;
    krow[i] = r;
    if (c < 16) { sb[i] = Kn + c * 8; sst[i] = 128; }
    else        { sb[i] = Kp + (c - 16) * 8; sst[i] = 64; }
    ksoff[i] = r * 192 + ((c ^ (r & 7)) * 8);
  }
  int vrow[2], vc[2], vsoff[2];
#pragma unroll
  for (int i = 0; i < 2; ++i) {
    int flat = i * 512 + tid;
    vrow[i] = flat >> 3; vc[i] = flat & 7;
    vsoff[i] = vrow[i] * 64 + ((vc[i] ^ (vrow[i] & 7)) * 8);
  }

  const int prow = wid * 16 + l15;
  const int pr7 = prow & 7;
  const float g = gain[h];

  for (int seg = 0; seg < 2; ++seg) {
    const int qt = seg ? pair : 15 - pair;
    const int q0 = qt * 128;
    const int nkt = 2 * qt + 2;
    const int sq = q0 + prow;

    bf16x8 qf[6];
    {
      const u16* qb_ = Qg + ((long)b * S_LEN + sq) * 3072 + h * 192;
#pragma unroll
      for (int f = 0; f < 6; ++f) qf[f] = *(const bf16x8*)(qb_ + f * 32 + 8 * l4);
    }
    // RoPE + gain on q_pe fragments (f=4,5): pairs are in-lane
#pragma unroll
    for (int f = 4; f < 6; ++f) {
      float4 cv = *(const float4*)(cosb + sq * 32 + (f - 4) * 16 + l4 * 4);
      float4 sv = *(const float4*)(sinb + sq * 32 + (f - 4) * 16 + l4 * 4);
      float cc[4] = {cv.x, cv.y, cv.z, cv.w};
      float ssn[4] = {sv.x, sv.y, sv.z, sv.w};
      u16* pq = (u16*)&qf[f];
#pragma unroll
      for (int pp = 0; pp < 4; ++pp) {
        float xe = bf2f(pq[2 * pp]), xo = bf2f(pq[2 * pp + 1]);
        pq[2 * pp]     = f2bf((xe * cc[pp] - xo * ssn[pp]) * g);
        pq[2 * pp + 1] = f2bf((xe * ssn[pp] + xo * cc[pp]) * g);
      }
    }

    f32x4 o[8] = {};
    float lsum = 0.f;

    u32x4 ka[3], va[2];
    // prologue: tile 0 -> LDS[0]; prefetch tile 1 into regs
#pragma unroll
    for (int i = 0; i < 3; ++i)
      ka[i] = *(const u32x4*)(sb[i] + (long)krow[i] * sst[i]);
#pragma unroll
    for (int i = 0; i < 2; ++i)
      va[i] = *(const u32x4*)(Vbh + (long)vrow[i] * S_LEN + vc[i] * 8);
#pragma unroll
    for (int i = 0; i < 3; ++i) *(u32x4*)(&Ks[0][ksoff[i]]) = ka[i];
#pragma unroll
    for (int i = 0; i < 2; ++i) *(u32x4*)(&VTs[0][vsoff[i]]) = va[i];
    if (nkt > 1) {
#pragma unroll
      for (int i = 0; i < 3; ++i)
        ka[i] = *(const u32x4*)(sb[i] + (long)(64 + krow[i]) * sst[i]);
#pragma unroll
      for (int i = 0; i < 2; ++i)
        va[i] = *(const u32x4*)(Vbh + (long)vrow[i] * S_LEN + 64 + vc[i] * 8);
    }
    __syncthreads();

    for (int it = 0; it < nkt; ++it) {
      const int cur = it & 1;

      f32x4 sacc[4] = {};
      __builtin_amdgcn_s_setprio(1);
#pragma unroll
      for (int f = 0; f < 6; ++f)
#pragma unroll
        for (int tf = 0; tf < 4; ++tf) {
          int row = tf * 16 + l15;
          bf16x8 kf = *(const bf16x8*)(&Ks[cur][row * 192 + (((f * 4 + l4) ^ (row & 7)) * 8)]);
          sacc[tf] = __builtin_amdgcn_mfma_f32_16x16x32_bf16(kf, qf[f], sacc[tf], 0, 0, 0);
        }
      __builtin_amdgcn_s_setprio(0);

      // stage next tile into other buffer; prefetch t+2 into regs
      if (it + 1 < nkt) {
#pragma unroll
        for (int i = 0; i < 3; ++i) *(u32x4*)(&Ks[cur ^ 1][ksoff[i]]) = ka[i];
#pragma unroll
        for (int i = 0; i < 2; ++i) *(u32x4*)(&VTs[cur ^ 1][vsoff[i]]) = va[i];
      }
      if (it + 2 < nkt) {
        int k0n = (it + 2) * 64;
#pragma unroll
        for (int i = 0; i < 3; ++i)
          ka[i] = *(const u32x4*)(sb[i] + (long)(k0n + krow[i]) * sst[i]);
#pragma unroll
        for (int i = 0; i < 2; ++i)
          va[i] = *(const u32x4*)(Vbh + (long)vrow[i] * S_LEN + k0n + vc[i] * 8);
      }

      // softmax with fixed reference (q pre-scaled in rmsnorm)
#pragma unroll
      for (int tf = 0; tf < 4; ++tf)
#pragma unroll
        for (int r = 0; r < 4; ++r) {
          float u = __builtin_amdgcn_exp2f(sacc[tf][r]);
          sacc[tf][r] = __builtin_amdgcn_exp2f(-86.56170245333781f *
                                               __builtin_amdgcn_rcpf(u + 1.0f));
        }
      if (it * 64 >= q0) {  // causal: kpos > qrow -> 0
        const int dthr = q0 + prow - it * 64 - l4 * 4;
#pragma unroll
        for (int tf = 0; tf < 4; ++tf)
#pragma unroll
          for (int r = 0; r < 4; ++r)
            if (tf * 16 + r > dthr) sacc[tf][r] = 0.f;
      }
#pragma unroll
      for (int tf = 0; tf < 4; ++tf)
#pragma unroll
        for (int r = 0; r < 4; ++r) lsum += sacc[tf][r];

#pragma unroll
      for (int tf = 0; tf < 4; ++tf) {
        u32x2 w;
        w.x = cvtpk(sacc[tf][0], sacc[tf][1]);
        w.y = cvtpk(sacc[tf][2], sacc[tf][3]);
        int chunk = tf * 2 + (l4 >> 1);
        *(u32x2*)(&Ps[prow * 64 + ((chunk ^ pr7) * 8) + (l4 & 1) * 4]) = w;
      }

      __builtin_amdgcn_s_setprio(1);
#pragma unroll
      for (int kk = 0; kk < 2; ++kk) {
        bf16x8 pf = *(const bf16x8*)(&Ps[prow * 64 + (((kk * 4 + l4) ^ pr7) * 8)]);
#pragma unroll
        for (int nf = 0; nf < 8; ++nf) {
          int vr = nf * 16 + l15;
          bf16x8 vf = *(const bf16x8*)(&VTs[cur][vr * 64 + (((kk * 4 + l4) ^ (vr & 7)) * 8)]);
          o[nf] = __builtin_amdgcn_mfma_f32_16x16x32_bf16(pf, vf, o[nf], 0, 0, 0);
        }
      }
      __builtin_amdgcn_s_setprio(0);

      __syncthreads();  // single barrier per tile: flip buffers
    }

    lsum += __shfl_xor(lsum, 16);
    lsum += __shfl_xor(lsum, 32);
    float inv[4];
#pragma unroll
    for (int r = 0; r < 4; ++r)
      inv[r] = __builtin_amdgcn_rcpf(__shfl(lsum, l4 * 4 + r));

    float yv[8][4], vvv[8][4];
    float ssum[4] = {0.f, 0.f, 0.f, 0.f}, dsum[4] = {0.f, 0.f, 0.f, 0.f};
    const u16* vb = Vcg + ((long)b * S_LEN + q0 + wid * 16) * 2048 + h * 128;
#pragma unroll
    for (int nf = 0; nf < 8; ++nf)
#pragma unroll
      for (int r = 0; r < 4; ++r) {
        float vv = bf2f(vb[(l4 * 4 + r) * 2048 + nf * 16 + l15]);
        float y = o[nf][r] * inv[r];
        vvv[nf][r] = vv; yv[nf][r] = y;
        ssum[r] += vv * vv; dsum[r] += y * vv;
      }
#pragma unroll
    for (int r = 0; r < 4; ++r) {
      ssum[r] += __shfl_xor(ssum[r], 1); ssum[r] += __shfl_xor(ssum[r], 2);
      ssum[r] += __shfl_xor(ssum[r], 4); ssum[r] += __shfl_xor(ssum[r], 8);
      dsum[r] += __shfl_xor(dsum[r], 1); dsum[r] += __shfl_xor(dsum[r], 2);
      dsum[r] += __shfl_xor(dsum[r], 4); dsum[r] += __shfl_xor(dsum[r], 8);
      dsum[r] *= __builtin_amdgcn_rcpf(fmaxf(ssum[r], 1e-12f));
    }
#pragma unroll
    for (int nf = 0; nf < 8; ++nf)
#pragma unroll
      for (int r = 0; r < 4; ++r) {
        long row = (long)b * S_LEN + q0 + wid * 16 + l4 * 4 + r;
        Yg[row * 2048 + h * 128 + nf * 16 + l15] = f2bf(yv[nf][r] - dsum[r] * vvv[nf][r]);
      }
  }
}

extern "C" void kernel_launch(void* const* d_in, const int* in_sizes, int n_in,
                              void* d_out, int out_size, void* d_ws, size_t ws_size,
                              hipStream_t stream) {
  const float* x       = (const float*)d_in[0];
  const float* wq_a    = (const float*)d_in[1];
  const float* q_norm  = (const float*)d_in[2];
  const float* wq_b    = (const float*)d_in[3];
  const float* q_gain  = (const float*)d_in[4];
  const float* wkv_a   = (const float*)d_in[5];
  const float* kv_norm = (const float*)d_in[6];
  const float* wkv_b   = (const float*)d_in[7];
  const float* wo      = (const float*)d_in[8];
  const float* fcos    = (const float*)d_in[9];
  const float* fsin    = (const float*)d_in[10];
  float* out = (float*)d_out;

  char* ws = (char*)d_ws;
  size_t off = 0;
  auto alloc = [&](size_t bytes) {
    char* pp = ws + off;
    off += (bytes + 255) & ~(size_t)255;
    return pp;
  };
  const long M = 4096;  // B*S
  u16* xb    = (u16*)alloc(M * 2048 * 2);
  u16* wcomb = (u16*)alloc(1408L * 2048 * 2);
  u16* wqbb  = (u16*)alloc(3072L * 768 * 2);
  u16* wkvbb = (u16*)alloc(4096L * 512 * 2);
  u16* wob   = (u16*)alloc(2048L * 2048 * 2);
  u16* qakv  = (u16*)alloc(M * 1408 * 2);
  u16* qb    = (u16*)alloc(M * 3072 * 2);
  u16* KbN   = (u16*)alloc(32L * 2048 * 128 * 2);
  u16* kpe   = (u16*)alloc(M * 64 * 2);
  u16* Vc    = (u16*)alloc(M * 2048 * 2);
  u16* VTb   = (u16*)alloc(32L * 128 * 2048 * 2);
  u16* Yb    = (u16*)alloc(M * 2048 * 2);

  const long n4_x = 2097152, n4_wqa = 393216, n4_wqb = 589824,
             n4_wkvb = 524288, n4_wo = 1048576, n4_wkvap = 327680;
  long e0 = n4_x, e1 = e0 + n4_wqa, e2 = e1 + n4_wqb, e3 = e2 + n4_wkvb,
       e4 = e3 + n4_wo, e5 = e4 + n4_wkvap;
  cast_all<<<(int)(e5 / 256), 256, 0, stream>>>(
      x, xb, e0, wq_a, wcomb, e1, wq_b, wqbb, e2, wkv_b, wkvbb, e3,
      wo, wob, e4, wkv_a, wcomb + 768L * 2048, e5);

  // fused: [q_a | kv_full] = x @ [wq_a; wkv_a]^T   (N=1408, 256x128 tall)
  gemm_tall<0><<<dim3(11, 16), 512, 0, stream>>>(xb, 2048, wcomb, 2048, qakv, 1408, nullptr, 2048);
  rmsnorm2_kernel<<<8192, 256, 0, stream>>>(qakv, q_norm, kv_norm, fcos, fsin, kpe);
  // GEMM2 (q-proj) + GEMM4 (kv-proj split) fused in one 448-block dispatch
  gemm256_dual<<<448, 512, 0, stream>>>(qakv, wqbb, qb, qakv + 768, wkvbb, KbN, Vc);
  v_transpose_kernel<<<dim3(32, 2, 32), 256, 0, stream>>>(Vc, VTb);
  attn_kernel<<<256, 512, 0, stream>>>(qb, KbN, kpe, VTb, Vc, fcos, fsin, q_gain, Yb);
  // out = y @ wo^T (f32 out)  (256x128 tall)
  gemm_tall<1><<<dim3(16, 16), 512, 0, stream>>>(Yb, 2048, wob, 2048, out, 2048, nullptr, 2048);
}